// Round 20
// baseline (1628.015 us; speedup 1.0000x reference)
//
#include <hip/hip_runtime.h>

typedef __bf16 bf16x8 __attribute__((ext_vector_type(8)));
typedef float f32x4 __attribute__((ext_vector_type(4)));
typedef unsigned short u16;
typedef unsigned int u32;

#define T_ 64
#define B_ 1024
#define H_ 1024
#define G4_ 4096
#define HB_ (B_ * H_)
#define NBLK_ 512
#define PARTSZ_ (B_ * 2 * 64)

__device__ inline u16 f2bf(float f) {
  u32 u = __float_as_uint(f);
  u32 r = (u + 0x7fffu + ((u >> 16) & 1u)) >> 16;  // RNE
  return (u16)r;
}

__device__ inline float bf2f(u16 v) { return __uint_as_float((u32)v << 16); }

__device__ inline uint2 cvt4(float4 v) {
  uint2 r;
  r.x = (u32)f2bf(v.x) | ((u32)f2bf(v.y) << 16);
  r.y = (u32)f2bf(v.z) | ((u32)f2bf(v.w) << 16);
  return r;
}

__device__ __forceinline__ void gload16(const void* g, void* l) {
  __builtin_amdgcn_global_load_lds(
      (const __attribute__((address_space(1))) unsigned int*)g,
      (__attribute__((address_space(3))) unsigned int*)l, 16, 0, 0);
}

// write-through 2B store: data lands at the coherence point (L3), never dirty in L2.
__device__ __forceinline__ void store_wt16(u16* p, u16 v) {
  asm volatile("global_store_short %0, %1, off sc0 sc1" :: "v"(p), "v"((u32)v) : "memory");
}

__device__ inline float fsig(float x) { return 1.f / (1.f + __expf(-x)); }
__device__ inline float ftanh(float x) {
  float e = __expf(2.f * x);
  return 1.f - 2.f / (e + 1.f);
}

// ---------- merged prep + gather (independent work, one launch):
// blocks [0,65536): gather XEall[t][b][:] = bf16(emb[x[b,t]])
// blocks [65536,70689): WihP/WhhP gate-interleaved bf16, bcP, h0slot, flags.
// Permutation: n' = (j>>4)*64 + gate*16 + (j&15)
__global__ void prep_gather_kernel(const int* __restrict__ x, const float* __restrict__ emb,
                                   const float* __restrict__ W_ih, const float* __restrict__ W_hh,
                                   const float* __restrict__ b_ih, const float* __restrict__ b_hh,
                                   const float* __restrict__ h0,
                                   u16* __restrict__ XEall,
                                   u16* __restrict__ WihP, u16* __restrict__ WhhP,
                                   float* __restrict__ bcP, u16* __restrict__ h0slot,
                                   u32* __restrict__ flags) {
  int bid = blockIdx.x, tid = threadIdx.x;
  if (bid < 65536) {
    int b = bid & 1023, tc = bid >> 10;
    int row = x[b * T_ + tc];
    int e = tid << 2;
    float4 v = *(const float4*)(emb + (size_t)row * H_ + e);
    *(uint2*)(XEall + ((size_t)tc * B_ + b) * H_ + e) = cvt4(v);
    return;
  }
  int pb = bid - 65536;
  if (pb < 4096) {
    int np = pb;
    int gate = (np >> 4) & 3;
    int j = ((np >> 6) << 4) | (np & 15);
    size_t srow = (size_t)(gate * 1024 + j) * 1024;
    int base = tid << 2;
    *(uint2*)(WihP + (size_t)np * 1024 + base) = cvt4(*(const float4*)(W_ih + srow + base));
    *(uint2*)(WhhP + (size_t)np * 1024 + base) = cvt4(*(const float4*)(W_hh + srow + base));
  } else if (pb < 5120) {
    int i = ((pb - 4096) * 256 + tid) << 2;
    *(uint2*)(h0slot + i) = cvt4(*(const float4*)(h0 + i));
  } else if (pb == 5120) {
#pragma unroll
    for (int q = 0; q < 16; ++q) {
      int np = q * 256 + tid;
      int gate = (np >> 4) & 3;
      int j = ((np >> 6) << 4) | (np & 15);
      int srcn = gate * 1024 + j;
      bcP[np] = b_ih[srcn] + b_hh[srcn];
    }
  } else {
    int idx = ((pb - 5121) * 256 + tid) << 2;  // 32 blocks x 1024 u32 = 32768
    *(uint4*)(flags + idx) = uint4{0u, 0u, 0u, 0u};
  }
}

// ---------- x-projection big GEMM, ONE dispatch: M = 65536, N = 4096, K = 1024.
// 256x128 tile, 512 threads = 8 waves (4m x 2n of 64x64), BK=64, single LDS buffer.
// Output written in REC-CONSUMPTION order: GX2[t][L][tid][16] where L = bx*8+by.
__global__ void __launch_bounds__(512, 4) xproj_kernel(
    const u16* __restrict__ XEc, const u16* __restrict__ WihP,
    const float* __restrict__ bcP, u16* __restrict__ GX2) {
  __shared__ char smem[49152];  // lsA [256][128B] (32K) + lsB [128][128B] (16K)
  const int tid = threadIdx.x;
  const int lane = tid & 63;
  const int wave = tid >> 6;
  const int wm = wave >> 1;  // [0,4)
  const int wn = wave & 1;   // [0,2)
  const int hbid = blockIdx.x;        // 8192 = 8 XCD x 1024
  const int xcd = hbid & 7;
  const int s10 = hbid >> 3;          // [0,1024)
  const int mg = s10 >> 6;            // [0,16) groups of 2 m-tiles
  const int rem = s10 & 63;
  const int n0 = (rem >> 1) * 128;    // 32 n-tiles, inner sweep
  const int m0 = (xcd * 32 + mg * 2 + (rem & 1)) * 256;  // 256 m-tiles, XCD-private

  const u16* srcA[4];
  const u16* srcB[2];
  int betaA[4], betaB[2];
#pragma unroll
  for (int s = 0; s < 4; ++s) {
    int beta = (s * 512 + tid) * 16;             // 0..32K
    int row = beta >> 7;                         // [0,256)
    int colu = (beta & 127) ^ ((row & 7) << 4);  // pre-swizzled source col
    srcA[s] = XEc + (size_t)(m0 + row) * 1024 + (colu >> 1);
    betaA[s] = beta;
  }
#pragma unroll
  for (int s = 0; s < 2; ++s) {
    int beta = (s * 512 + tid) * 16;             // 0..16K
    int row = beta >> 7;                         // [0,128)
    int colu = (beta & 127) ^ ((row & 7) << 4);
    srcB[s] = WihP + (size_t)(n0 + row) * 1024 + (colu >> 1);
    betaB[s] = 32768 + beta;
  }

  f32x4 acc[4][4] = {};
  const int rsel = lane & 15;
  const int ksel = (lane >> 4) << 4;

  for (int kt = 0; kt < 16; ++kt) {
#pragma unroll
    for (int s = 0; s < 4; ++s) gload16(srcA[s], smem + betaA[s]);
#pragma unroll
    for (int s = 0; s < 2; ++s) gload16(srcB[s], smem + betaB[s]);
#pragma unroll
    for (int s = 0; s < 4; ++s) srcA[s] += 64;
#pragma unroll
    for (int s = 0; s < 2; ++s) srcB[s] += 64;
    __syncthreads();
#pragma unroll
    for (int kk = 0; kk < 2; ++kk) {
      const int colb = kk * 64 + ksel;
      bf16x8 af[4], bfr[4];
#pragma unroll
      for (int mi = 0; mi < 4; ++mi) {
        int row = wm * 64 + mi * 16 + rsel;
        af[mi] = *(const bf16x8*)(smem + row * 128 + (colb ^ ((row & 7) << 4)));
      }
#pragma unroll
      for (int ni = 0; ni < 4; ++ni) {
        int row = wn * 64 + ni * 16 + rsel;
        bfr[ni] = *(const bf16x8*)(smem + 32768 + row * 128 + (colb ^ ((row & 7) << 4)));
      }
#pragma unroll
      for (int mi = 0; mi < 4; ++mi)
#pragma unroll
        for (int ni = 0; ni < 4; ++ni)
          acc[mi][ni] = __builtin_amdgcn_mfma_f32_16x16x32_bf16(af[mi], bfr[ni], acc[mi][ni], 0, 0, 0);
    }
    __syncthreads();
  }

  // epilogue: + bias, write in rec-consumption layout (coalesced 32B per (mi))
  const int rbase = (lane >> 4) << 2;
  const int cbase = lane & 15;
  float bc[4];
#pragma unroll
  for (int ni = 0; ni < 4; ++ni) bc[ni] = bcP[n0 + wn * 64 + ni * 16 + cbase];
  const int tstep = m0 >> 10;                 // step index
  const int bxp = (n0 >> 6) + wn;             // rec n-tile [0,64)
  const int brow0 = (m0 & 1023) + wm * 64;    // batch-row base of this wave
#pragma unroll
  for (int mi = 0; mi < 4; ++mi) {
    int brow = brow0 + mi * 16;
    int byp = brow >> 7;                      // rec m-tile [0,8)
    int qmp = (brow >> 4) & 7;                // rec wave
    int tidp = qmp * 64 + (rbase << 2) + cbase;
    size_t gb = (((size_t)tstep * NBLK_ + bxp * 8 + byp) * 512 + tidp) * 16;
    u16 vals[16];
#pragma unroll
    for (int ni = 0; ni < 4; ++ni)
#pragma unroll
      for (int r = 0; r < 4; ++r)
        vals[ni * 4 + r] = f2bf(acc[mi][ni][r] + bc[ni]);
    *(uint4*)(GX2 + gb) = *(const uint4*)vals;
    *(uint4*)(GX2 + gb + 8) = *(const uint4*)(vals + 8);
  }
}

// ---------- persistent recurrent kernel: 512 blocks x 512 thr, NO fences.
// 3-deep A/B LDS ring (prefetch distance 2 covers the L3 latency of the always-cold
// h loads) + GX in REGISTERS via NT loads (no L2/L3 pollution, no LDS staging).
// h via WT stores + fresh ring; per-group flag barrier. c in registers.
__global__ void __launch_bounds__(512, 4) rec_kernel(
    const u16* __restrict__ h0slot, u16* __restrict__ hring,
    const u16* __restrict__ WhhP, const u16* __restrict__ GX2,
    const float* __restrict__ c0, float* __restrict__ partAll,
    const float* __restrict__ Wout, u32* __restrict__ flags) {
  __shared__ char smem[73728];  // A ring 3x16K @0 | B ring 3x8K @49152
  const int tid = threadIdx.x;
  const int lane = tid & 63;
  const int qm = tid >> 6;  // wave = m-slice [0,8), 16 rows each
  const int hbid = blockIdx.x;
  const int L = (hbid & 7) * 64 + (hbid >> 3);  // XCD swizzle: W n-slice per XCD
  const int bx = L >> 3;   // [0,64): n-tile
  const int by = L & 7;    // [0,8): m-tile
  const int n0 = bx * 64;
  const int m0 = by * 128;

  int offA[2], betaS[2];
  int offB, betaB;
#pragma unroll
  for (int s = 0; s < 2; ++s) {
    int beta = (s * 512 + tid) * 16;             // 0..16K
    int row = beta >> 7;
    int colu = (beta & 127) ^ ((row & 7) << 4);
    offA[s] = (m0 + row) * 1024 + (colu >> 1);
    betaS[s] = beta;
  }
  {
    int beta = tid * 16;                         // 0..8K
    int row = beta >> 7;
    int colu = (beta & 127) ^ ((row & 7) << 4);
    offB = (n0 + row) * 1024 + (colu >> 1);
    betaB = beta;
  }

  const int rsel = lane & 15;
  const int ksel = (lane >> 4) << 4;
  const int rbase = (lane >> 4) << 2;
  const int cbase = lane & 15;
  const int j = bx * 16 + cbase;
  const float w0 = Wout[j], w1 = Wout[1024 + j];

  // GX2 pointer for this (block, thread): step stride = NBLK_*512*16 u16
  const u16* gptr = GX2 + ((size_t)(bx * 8 + by) * 512 + tid) * 16;

  // cell state lives in registers for the whole sequence (4 rows per thread)
  float creg[4];
#pragma unroll
  for (int r = 0; r < 4; ++r)
    creg[r] = c0[(size_t)(m0 + qm * 16 + rbase + r) * H_ + j];

#pragma unroll 1
  for (int t = 0; t < T_; ++t) {
    // GX(t) -> registers via NT loads (read-once; no cache allocation).
    // Oldest in queue; drained by kt0's vmcnt(6); consumed after kt15's vmcnt(0).
    const u16* gp = gptr + (size_t)t * (NBLK_ * 512 * 16);
    uint4 gxa, gxb;
    asm volatile(
        "global_load_dwordx4 %0, %2, off nt\n\t"
        "global_load_dwordx4 %1, %2, off offset:16 nt"
        : "=v"(gxa), "=v"(gxb) : "v"(gp) : "memory");

    // B(Whh) tile 0 -> slot 0: barrier-independent, issue before the poll.
    gload16(WhhP + offB, smem + 49152 + betaB);

    if (t) {
      // group barrier: wait for the 64 same-by blocks (they wrote our h rows, step t-1)
      if (tid < 64) {
        const u32* fg = flags + (size_t)(t - 1) * NBLK_ + by * 64;
        int guard = 0;
        while (true) {
          u32 v = __hip_atomic_load(fg + tid, __ATOMIC_RELAXED, __HIP_MEMORY_SCOPE_AGENT);
          if (__all(v != 0)) break;
          __builtin_amdgcn_s_sleep(4);
          if (++guard > (1 << 18)) break;  // bounded: fail loud, never hang
        }
      }
      __syncthreads();  // no acquire fence: h buffer fresh, L2 never cached it
    }

    // h ring: step t reads hring[t-1] (t=0 -> h0slot), writes hring[t]
    const u16* hbR = t ? (hring + (size_t)(t - 1) * HB_) : h0slot;
    u16* hbW = hring + (size_t)t * HB_;

    // A tile 0 + full tile 1 -> ring slots 0,1 (post-barrier)
#pragma unroll
    for (int s = 0; s < 2; ++s) gload16(hbR + offA[s], smem + betaS[s]);
#pragma unroll
    for (int s = 0; s < 2; ++s) gload16(hbR + offA[s] + 64, smem + 16384 + betaS[s]);
    gload16(WhhP + offB + 64, smem + 49152 + 8192 + betaB);

    f32x4 acc[4] = {};
#pragma unroll
    for (int kt = 0; kt < 16; ++kt) {
      const int cur = kt % 3;
      const int abase = cur * 16384;
      const int bbase = 49152 + cur * 8192;
      if (kt < 14) {
        const int nxt = (kt + 2) % 3;
        const int kadv = (kt + 2) * 64;
#pragma unroll
        for (int s = 0; s < 2; ++s)
          gload16(hbR + offA[s] + kadv, smem + nxt * 16384 + betaS[s]);
        gload16(WhhP + offB + kadv, smem + 49152 + nxt * 8192 + betaB);
        // 3-deep: <=2 tiles beyond current in flight; vmcnt(6) drains through tile kt
        // (and GX at kt0, which is older than tile 0).
        asm volatile("s_waitcnt vmcnt(6)" ::: "memory");
      } else if (kt == 14) {
        asm volatile("s_waitcnt vmcnt(3)" ::: "memory");
      } else {
        asm volatile("s_waitcnt vmcnt(0)" ::: "memory");
      }
      __builtin_amdgcn_s_barrier();
      __builtin_amdgcn_sched_barrier(0);
#pragma unroll
      for (int kk = 0; kk < 2; ++kk) {
        const int colb = kk * 64 + ksel;
        bf16x8 af, bfr[4];
        {
          int row = qm * 16 + rsel;
          af = *(const bf16x8*)(smem + abase + row * 128 + (colb ^ ((row & 7) << 4)));
        }
#pragma unroll
        for (int ni = 0; ni < 4; ++ni) {
          int row = ni * 16 + rsel;
          bfr[ni] = *(const bf16x8*)(smem + bbase + row * 128 + (colb ^ ((row & 7) << 4)));
        }
#pragma unroll
        for (int ni = 0; ni < 4; ++ni)
          acc[ni] = __builtin_amdgcn_mfma_f32_16x16x32_bf16(af, bfr[ni], acc[ni], 0, 0, 0);
      }
      __builtin_amdgcn_s_barrier();
      __builtin_amdgcn_sched_barrier(0);
    }

    // epilogue pass 1: gates = acc + gx(REGISTERS); cell on register c; WT h stores
    u16 gxs[16];
    *(uint4*)gxs = gxa;
    *(uint4*)(gxs + 8) = gxb;
#pragma unroll
    for (int r = 0; r < 4; ++r) {
      int b = m0 + qm * 16 + rbase + r;
      float gi = acc[0][r] + bf2f(gxs[r]);
      float gf = acc[1][r] + bf2f(gxs[4 + r]);
      float gg = acc[2][r] + bf2f(gxs[8 + r]);
      float go = acc[3][r] + bf2f(gxs[12 + r]);
      float c2 = fsig(gf) * creg[r] + fsig(gi) * ftanh(gg);
      float h2 = fsig(go) * ftanh(c2);
      creg[r] = c2;
      store_wt16(hbW + (size_t)b * H_ + j, f2bf(h2));
    }

    // drain h stores -> coherence point, then signal
    asm volatile("s_waitcnt vmcnt(0)" ::: "memory");
    __syncthreads();
    if (tid == 0)
      __hip_atomic_store(flags + (size_t)t * NBLK_ + by * 64 + bx, 1u,
                         __ATOMIC_RELAXED, __HIP_MEMORY_SCOPE_AGENT);

    // epilogue pass 2 (off critical path): head partials from creg
    float* partW = partAll + (size_t)t * PARTSZ_;
#pragma unroll
    for (int r = 0; r < 4; ++r) {
      int b = m0 + qm * 16 + rbase + r;
      float p0 = creg[r] * w0, p1 = creg[r] * w1;
#pragma unroll
      for (int off = 1; off < 16; off <<= 1) {
        p0 += __shfl_xor(p0, off);
        p1 += __shfl_xor(p1, off);
      }
      if (cbase == 0) {
        partW[(b << 7) + bx] = p0;
        partW[(b << 7) + 64 + bx] = p1;
      }
    }
  }
}

// ---------- final: reduce ALL steps' partials -> out[t] log-softmax; t=63 also raw out_final
__global__ void final_kernel(const float* __restrict__ partAll, const float* __restrict__ bout,
                             float* __restrict__ out) {
  int gid = blockIdx.x * 256 + threadIdx.x;  // 131072 = 64 t x 1024 b x 2 cls
  int t = gid >> 11;
  int r = gid & 2047;
  int b = r >> 1, cls = r & 1;
  const float4* pp = (const float4*)(partAll + (size_t)t * PARTSZ_ + (b << 7) + cls * 64);
  float4 sv = {0.f, 0.f, 0.f, 0.f};
#pragma unroll
  for (int q = 0; q < 16; ++q) {
    float4 v = pp[q];
    sv.x += v.x; sv.y += v.y; sv.z += v.z; sv.w += v.w;
  }
  float l = sv.x + sv.y + sv.z + sv.w + bout[cls];
  float other = __shfl_xor(l, 1);
  float m = fmaxf(l, other);
  float ls = m + __logf(__expf(l - m) + __expf(other - m));
  out[(size_t)t * (B_ * 2) + b * 2 + cls] = l - ls;
  if (t == 63) out[(size_t)T_ * (B_ * 2) + b * 2 + cls] = l;  // out_final raw
}

extern "C" void kernel_launch(void* const* d_in, const int* in_sizes, int n_in,
                              void* d_out, int out_size, void* d_ws, size_t ws_size,
                              hipStream_t stream) {
  const int* x      = (const int*)d_in[0];
  const float* emb  = (const float*)d_in[1];
  const float* W_ih = (const float*)d_in[2];
  const float* W_hh = (const float*)d_in[3];
  const float* b_ih = (const float*)d_in[4];
  const float* b_hh = (const float*)d_in[5];
  const float* W_out = (const float*)d_in[6];
  const float* b_out = (const float*)d_in[7];
  const float* h0   = (const float*)d_in[8];
  const float* c0   = (const float*)d_in[9];
  float* out = (float*)d_out;

  // workspace (~691 MB): XEall region is DEAD after xproj -> reused as the h ring.
  char* w = (char*)d_ws;
  u16* WihP = (u16*)w;   w += (size_t)G4_ * H_ * 2;             // 8 MB
  u16* WhhP = (u16*)w;   w += (size_t)G4_ * H_ * 2;             // 8 MB
  u16* XEall = (u16*)w;  w += (size_t)T_ * HB_ * 2;             // 128 MB (= hring[1..64])
  u16* GX2  = (u16*)w;   w += (size_t)T_ * NBLK_ * 512 * 16 * 2;  // 512 MB rec-ordered
  u16* h0slot = (u16*)w; w += (size_t)HB_ * 2;                  // 2 MB (hring[0])
  float* bcP = (float*)w;     w += (size_t)G4_ * 4;
  float* partAll = (float*)w; w += (size_t)T_ * PARTSZ_ * 4;    // 32 MB
  u32* flags = (u32*)w;       w += (size_t)T_ * NBLK_ * 4;      // 128 KB

  prep_gather_kernel<<<70689, 256, 0, stream>>>(x, emb, W_ih, W_hh, b_ih, b_hh, h0,
                                                XEall, WihP, WhhP, bcP, h0slot, flags);
  xproj_kernel<<<8192, 512, 0, stream>>>(XEall, WihP, bcP, GX2);
  rec_kernel<<<NBLK_, 512, 0, stream>>>(h0slot, XEall /*hring[1..]*/, WhhP, GX2, c0,
                                        partAll, W_out, flags);
  final_kernel<<<512, 256, 0, stream>>>(partAll, b_out, out);
}

// Round 21
// 1571.778 us; speedup vs baseline: 1.0358x; 1.0358x over previous
//
#include <hip/hip_runtime.h>

typedef __bf16 bf16x8 __attribute__((ext_vector_type(8)));
typedef float f32x4 __attribute__((ext_vector_type(4)));
typedef unsigned short u16;
typedef unsigned int u32;

#define T_ 64
#define B_ 1024
#define H_ 1024
#define G4_ 4096
#define HB_ (B_ * H_)
#define NBLK_ 512
#define PARTSZ_ (B_ * 2 * 64)

__device__ inline u16 f2bf(float f) {
  u32 u = __float_as_uint(f);
  u32 r = (u + 0x7fffu + ((u >> 16) & 1u)) >> 16;  // RNE
  return (u16)r;
}

__device__ inline float bf2f(u16 v) { return __uint_as_float((u32)v << 16); }

__device__ inline uint2 cvt4(float4 v) {
  uint2 r;
  r.x = (u32)f2bf(v.x) | ((u32)f2bf(v.y) << 16);
  r.y = (u32)f2bf(v.z) | ((u32)f2bf(v.w) << 16);
  return r;
}

__device__ __forceinline__ void gload16(const void* g, void* l) {
  __builtin_amdgcn_global_load_lds(
      (const __attribute__((address_space(1))) unsigned int*)g,
      (__attribute__((address_space(3))) unsigned int*)l, 16, 0, 0);
}

// write-through 2B store: data lands at the coherence point (L3), never dirty in L2.
__device__ __forceinline__ void store_wt16(u16* p, u16 v) {
  asm volatile("global_store_short %0, %1, off sc0 sc1" :: "v"(p), "v"((u32)v) : "memory");
}

__device__ inline float fsig(float x) { return 1.f / (1.f + __expf(-x)); }
__device__ inline float ftanh(float x) {
  float e = __expf(2.f * x);
  return 1.f - 2.f / (e + 1.f);
}

// ---------- merged prep + gather (independent work, one launch; r20-proven):
// blocks [0,65536): gather XEall[t][b][:] = bf16(emb[x[b,t]])
// blocks [65536,70689): WihP/WhhP gate-interleaved bf16, bcP, h0slot, flags.
// Permutation: n' = (j>>4)*64 + gate*16 + (j&15)
__global__ void prep_gather_kernel(const int* __restrict__ x, const float* __restrict__ emb,
                                   const float* __restrict__ W_ih, const float* __restrict__ W_hh,
                                   const float* __restrict__ b_ih, const float* __restrict__ b_hh,
                                   const float* __restrict__ h0,
                                   u16* __restrict__ XEall,
                                   u16* __restrict__ WihP, u16* __restrict__ WhhP,
                                   float* __restrict__ bcP, u16* __restrict__ h0slot,
                                   u32* __restrict__ flags) {
  int bid = blockIdx.x, tid = threadIdx.x;
  if (bid < 65536) {
    int b = bid & 1023, tc = bid >> 10;
    int row = x[b * T_ + tc];
    int e = tid << 2;
    float4 v = *(const float4*)(emb + (size_t)row * H_ + e);
    *(uint2*)(XEall + ((size_t)tc * B_ + b) * H_ + e) = cvt4(v);
    return;
  }
  int pb = bid - 65536;
  if (pb < 4096) {
    int np = pb;
    int gate = (np >> 4) & 3;
    int j = ((np >> 6) << 4) | (np & 15);
    size_t srow = (size_t)(gate * 1024 + j) * 1024;
    int base = tid << 2;
    *(uint2*)(WihP + (size_t)np * 1024 + base) = cvt4(*(const float4*)(W_ih + srow + base));
    *(uint2*)(WhhP + (size_t)np * 1024 + base) = cvt4(*(const float4*)(W_hh + srow + base));
  } else if (pb < 5120) {
    int i = ((pb - 4096) * 256 + tid) << 2;
    *(uint2*)(h0slot + i) = cvt4(*(const float4*)(h0 + i));
  } else if (pb == 5120) {
#pragma unroll
    for (int q = 0; q < 16; ++q) {
      int np = q * 256 + tid;
      int gate = (np >> 4) & 3;
      int j = ((np >> 6) << 4) | (np & 15);
      int srcn = gate * 1024 + j;
      bcP[np] = b_ih[srcn] + b_hh[srcn];
    }
  } else {
    int idx = ((pb - 5121) * 256 + tid) << 2;  // 32 blocks x 1024 u32 = 32768
    *(uint4*)(flags + idx) = uint4{0u, 0u, 0u, 0u};
  }
}

// ---------- x-projection big GEMM, ONE dispatch: M = 65536, N = 4096, K = 1024.
// 256x128 tile, 512 threads = 8 waves (4m x 2n of 64x64), BK=64, single LDS buffer.
// Output written in REC-CONSUMPTION order: GX2[t][L][tid][16] where L = bx*8+by.
__global__ void __launch_bounds__(512, 4) xproj_kernel(
    const u16* __restrict__ XEc, const u16* __restrict__ WihP,
    const float* __restrict__ bcP, u16* __restrict__ GX2) {
  __shared__ char smem[49152];  // lsA [256][128B] (32K) + lsB [128][128B] (16K)
  const int tid = threadIdx.x;
  const int lane = tid & 63;
  const int wave = tid >> 6;
  const int wm = wave >> 1;  // [0,4)
  const int wn = wave & 1;   // [0,2)
  const int hbid = blockIdx.x;        // 8192 = 8 XCD x 1024
  const int xcd = hbid & 7;
  const int s10 = hbid >> 3;          // [0,1024)
  const int mg = s10 >> 6;            // [0,16) groups of 2 m-tiles
  const int rem = s10 & 63;
  const int n0 = (rem >> 1) * 128;    // 32 n-tiles, inner sweep
  const int m0 = (xcd * 32 + mg * 2 + (rem & 1)) * 256;  // 256 m-tiles, XCD-private

  const u16* srcA[4];
  const u16* srcB[2];
  int betaA[4], betaB[2];
#pragma unroll
  for (int s = 0; s < 4; ++s) {
    int beta = (s * 512 + tid) * 16;             // 0..32K
    int row = beta >> 7;                         // [0,256)
    int colu = (beta & 127) ^ ((row & 7) << 4);  // pre-swizzled source col
    srcA[s] = XEc + (size_t)(m0 + row) * 1024 + (colu >> 1);
    betaA[s] = beta;
  }
#pragma unroll
  for (int s = 0; s < 2; ++s) {
    int beta = (s * 512 + tid) * 16;             // 0..16K
    int row = beta >> 7;                         // [0,128)
    int colu = (beta & 127) ^ ((row & 7) << 4);
    srcB[s] = WihP + (size_t)(n0 + row) * 1024 + (colu >> 1);
    betaB[s] = 32768 + beta;
  }

  f32x4 acc[4][4] = {};
  const int rsel = lane & 15;
  const int ksel = (lane >> 4) << 4;

  for (int kt = 0; kt < 16; ++kt) {
#pragma unroll
    for (int s = 0; s < 4; ++s) gload16(srcA[s], smem + betaA[s]);
#pragma unroll
    for (int s = 0; s < 2; ++s) gload16(srcB[s], smem + betaB[s]);
#pragma unroll
    for (int s = 0; s < 4; ++s) srcA[s] += 64;
#pragma unroll
    for (int s = 0; s < 2; ++s) srcB[s] += 64;
    __syncthreads();
#pragma unroll
    for (int kk = 0; kk < 2; ++kk) {
      const int colb = kk * 64 + ksel;
      bf16x8 af[4], bfr[4];
#pragma unroll
      for (int mi = 0; mi < 4; ++mi) {
        int row = wm * 64 + mi * 16 + rsel;
        af[mi] = *(const bf16x8*)(smem + row * 128 + (colb ^ ((row & 7) << 4)));
      }
#pragma unroll
      for (int ni = 0; ni < 4; ++ni) {
        int row = wn * 64 + ni * 16 + rsel;
        bfr[ni] = *(const bf16x8*)(smem + 32768 + row * 128 + (colb ^ ((row & 7) << 4)));
      }
#pragma unroll
      for (int mi = 0; mi < 4; ++mi)
#pragma unroll
        for (int ni = 0; ni < 4; ++ni)
          acc[mi][ni] = __builtin_amdgcn_mfma_f32_16x16x32_bf16(af[mi], bfr[ni], acc[mi][ni], 0, 0, 0);
    }
    __syncthreads();
  }

  // epilogue: + bias, write in rec-consumption layout (coalesced 32B per (mi))
  const int rbase = (lane >> 4) << 2;
  const int cbase = lane & 15;
  float bc[4];
#pragma unroll
  for (int ni = 0; ni < 4; ++ni) bc[ni] = bcP[n0 + wn * 64 + ni * 16 + cbase];
  const int tstep = m0 >> 10;                 // step index
  const int bxp = (n0 >> 6) + wn;             // rec n-tile [0,64)
  const int brow0 = (m0 & 1023) + wm * 64;    // batch-row base of this wave
#pragma unroll
  for (int mi = 0; mi < 4; ++mi) {
    int brow = brow0 + mi * 16;
    int byp = brow >> 7;                      // rec m-tile [0,8)
    int qmp = (brow >> 4) & 7;                // rec wave
    int tidp = qmp * 64 + (rbase << 2) + cbase;
    size_t gb = (((size_t)tstep * NBLK_ + bxp * 8 + byp) * 512 + tidp) * 16;
    u16 vals[16];
#pragma unroll
    for (int ni = 0; ni < 4; ++ni)
#pragma unroll
      for (int r = 0; r < 4; ++r)
        vals[ni * 4 + r] = f2bf(acc[mi][ni][r] + bc[ni]);
    *(uint4*)(GX2 + gb) = *(const uint4*)vals;
    *(uint4*)(GX2 + gb + 8) = *(const uint4*)(vals + 8);
  }
}

// ---------- persistent recurrent kernel (r19-proven, best measured): 512 x 512,
// 2-deep A/B LDS dbuf + GX in REGISTERS via NT loads. NO fences; h via WT stores +
// fresh ring; per-group flag barrier; c in registers.
__global__ void __launch_bounds__(512, 4) rec_kernel(
    const u16* __restrict__ h0slot, u16* __restrict__ hring,
    const u16* __restrict__ WhhP, const u16* __restrict__ GX2,
    const float* __restrict__ c0, float* __restrict__ partAll,
    const float* __restrict__ Wout, u32* __restrict__ flags) {
  __shared__ char smem[49152];  // A dbuf 2x16K @0 | B dbuf 2x8K @32768
  const int tid = threadIdx.x;
  const int lane = tid & 63;
  const int qm = tid >> 6;  // wave = m-slice [0,8), 16 rows each
  const int hbid = blockIdx.x;
  const int L = (hbid & 7) * 64 + (hbid >> 3);  // XCD swizzle: W n-slice per XCD
  const int bx = L >> 3;   // [0,64): n-tile
  const int by = L & 7;    // [0,8): m-tile
  const int n0 = bx * 64;
  const int m0 = by * 128;

  int offA[2], betaS[2];
  int offB, betaB;
#pragma unroll
  for (int s = 0; s < 2; ++s) {
    int beta = (s * 512 + tid) * 16;             // 0..16K
    int row = beta >> 7;
    int colu = (beta & 127) ^ ((row & 7) << 4);
    offA[s] = (m0 + row) * 1024 + (colu >> 1);
    betaS[s] = beta;
  }
  {
    int beta = tid * 16;                         // 0..8K
    int row = beta >> 7;
    int colu = (beta & 127) ^ ((row & 7) << 4);
    offB = (n0 + row) * 1024 + (colu >> 1);
    betaB = beta;
  }

  const int rsel = lane & 15;
  const int ksel = (lane >> 4) << 4;
  const int rbase = (lane >> 4) << 2;
  const int cbase = lane & 15;
  const int j = bx * 16 + cbase;
  const float w0 = Wout[j], w1 = Wout[1024 + j];

  // GX2 pointer for this (block, thread): step stride = NBLK_*512*16 u16
  const u16* gptr = GX2 + ((size_t)(bx * 8 + by) * 512 + tid) * 16;

  // cell state lives in registers for the whole sequence (4 rows per thread)
  float creg[4];
#pragma unroll
  for (int r = 0; r < 4; ++r)
    creg[r] = c0[(size_t)(m0 + qm * 16 + rbase + r) * H_ + j];

#pragma unroll 1
  for (int t = 0; t < T_; ++t) {
    // GX(t) -> registers via NT loads (read-once: don't allocate in L2/L3).
    // Oldest in vmcnt queue; drained by kt0's vmcnt(3); used only after kt15's vmcnt(0).
    const u16* gp = gptr + (size_t)t * (NBLK_ * 512 * 16);
    uint4 gxa, gxb;
    asm volatile(
        "global_load_dwordx4 %0, %2, off nt\n\t"
        "global_load_dwordx4 %1, %2, off offset:16 nt"
        : "=v"(gxa), "=v"(gxb) : "v"(gp) : "memory");

    // B(Whh) tile 0 -> buffer 0: barrier-independent, issue before the poll.
    gload16(WhhP + offB, smem + 32768 + betaB);

    if (t) {
      // group barrier: wait for the 64 same-by blocks (they wrote our h rows, step t-1)
      if (tid < 64) {
        const u32* fg = flags + (size_t)(t - 1) * NBLK_ + by * 64;
        int guard = 0;
        while (true) {
          u32 v = __hip_atomic_load(fg + tid, __ATOMIC_RELAXED, __HIP_MEMORY_SCOPE_AGENT);
          if (__all(v != 0)) break;
          __builtin_amdgcn_s_sleep(4);
          if (++guard > (1 << 18)) break;  // bounded: fail loud, never hang
        }
      }
      __syncthreads();  // no acquire fence: h buffer fresh, L2 never cached it
    }

    // h ring: step t reads hring[t-1] (t=0 -> h0slot), writes hring[t]
    const u16* hbR = t ? (hring + (size_t)(t - 1) * HB_) : h0slot;
    u16* hbW = hring + (size_t)t * HB_;

    // A(h) tile 0 (needs the barrier)
#pragma unroll
    for (int s = 0; s < 2; ++s) gload16(hbR + offA[s], smem + betaS[s]);

    f32x4 acc[4] = {};
#pragma unroll
    for (int kt = 0; kt < 16; ++kt) {
      const int cur = kt & 1;
      const int abase = cur * 16384;
      const int bbase = 32768 + cur * 8192;
      if (kt < 15) {
        const int nab = (cur ^ 1) * 16384;
        const int nbb = 32768 + (cur ^ 1) * 8192;
        const int kadv = (kt + 1) * 64;
#pragma unroll
        for (int s = 0; s < 2; ++s) gload16(hbR + offA[s] + kadv, smem + nab + betaS[s]);
        gload16(WhhP + offB + kadv, smem + nbb + betaB);
        // steady: queue = [3 tile_kt, 3 tile_kt+1] -> vmcnt(3) drains tile kt.
        // kt0: queue = [2 GX, 1 B0, 2 A0, 3 tile1] -> vmcnt(3) drains GX+B0+A0.
        asm volatile("s_waitcnt vmcnt(3)" ::: "memory");
      } else {
        asm volatile("s_waitcnt vmcnt(0)" ::: "memory");
      }
      __builtin_amdgcn_s_barrier();
      __builtin_amdgcn_sched_barrier(0);
#pragma unroll
      for (int kk = 0; kk < 2; ++kk) {
        const int colb = kk * 64 + ksel;
        bf16x8 af, bfr[4];
        {
          int row = qm * 16 + rsel;
          af = *(const bf16x8*)(smem + abase + row * 128 + (colb ^ ((row & 7) << 4)));
        }
#pragma unroll
        for (int ni = 0; ni < 4; ++ni) {
          int row = ni * 16 + rsel;
          bfr[ni] = *(const bf16x8*)(smem + bbase + row * 128 + (colb ^ ((row & 7) << 4)));
        }
#pragma unroll
        for (int ni = 0; ni < 4; ++ni)
          acc[ni] = __builtin_amdgcn_mfma_f32_16x16x32_bf16(af, bfr[ni], acc[ni], 0, 0, 0);
      }
      __builtin_amdgcn_s_barrier();
      __builtin_amdgcn_sched_barrier(0);
    }

    // epilogue pass 1: gates = acc + gx(REGISTERS); cell on register c; WT h stores
    u16 gxs[16];
    *(uint4*)gxs = gxa;
    *(uint4*)(gxs + 8) = gxb;
#pragma unroll
    for (int r = 0; r < 4; ++r) {
      int b = m0 + qm * 16 + rbase + r;
      float gi = acc[0][r] + bf2f(gxs[r]);
      float gf = acc[1][r] + bf2f(gxs[4 + r]);
      float gg = acc[2][r] + bf2f(gxs[8 + r]);
      float go = acc[3][r] + bf2f(gxs[12 + r]);
      float c2 = fsig(gf) * creg[r] + fsig(gi) * ftanh(gg);
      float h2 = fsig(go) * ftanh(c2);
      creg[r] = c2;
      store_wt16(hbW + (size_t)b * H_ + j, f2bf(h2));
    }

    // drain h stores -> coherence point, then signal
    asm volatile("s_waitcnt vmcnt(0)" ::: "memory");
    __syncthreads();
    if (tid == 0)
      __hip_atomic_store(flags + (size_t)t * NBLK_ + by * 64 + bx, 1u,
                         __ATOMIC_RELAXED, __HIP_MEMORY_SCOPE_AGENT);

    // epilogue pass 2 (off critical path): head partials from creg
    float* partW = partAll + (size_t)t * PARTSZ_;
#pragma unroll
    for (int r = 0; r < 4; ++r) {
      int b = m0 + qm * 16 + rbase + r;
      float p0 = creg[r] * w0, p1 = creg[r] * w1;
#pragma unroll
      for (int off = 1; off < 16; off <<= 1) {
        p0 += __shfl_xor(p0, off);
        p1 += __shfl_xor(p1, off);
      }
      if (cbase == 0) {
        partW[(b << 7) + bx] = p0;
        partW[(b << 7) + 64 + bx] = p1;
      }
    }
  }
}

// ---------- final: reduce ALL steps' partials -> out[t] log-softmax; t=63 also raw out_final
__global__ void final_kernel(const float* __restrict__ partAll, const float* __restrict__ bout,
                             float* __restrict__ out) {
  int gid = blockIdx.x * 256 + threadIdx.x;  // 131072 = 64 t x 1024 b x 2 cls
  int t = gid >> 11;
  int r = gid & 2047;
  int b = r >> 1, cls = r & 1;
  const float4* pp = (const float4*)(partAll + (size_t)t * PARTSZ_ + (b << 7) + cls * 64);
  float4 sv = {0.f, 0.f, 0.f, 0.f};
#pragma unroll
  for (int q = 0; q < 16; ++q) {
    float4 v = pp[q];
    sv.x += v.x; sv.y += v.y; sv.z += v.z; sv.w += v.w;
  }
  float l = sv.x + sv.y + sv.z + sv.w + bout[cls];
  float other = __shfl_xor(l, 1);
  float m = fmaxf(l, other);
  float ls = m + __logf(__expf(l - m) + __expf(other - m));
  out[(size_t)t * (B_ * 2) + b * 2 + cls] = l - ls;
  if (t == 63) out[(size_t)T_ * (B_ * 2) + b * 2 + cls] = l;  // out_final raw
}

extern "C" void kernel_launch(void* const* d_in, const int* in_sizes, int n_in,
                              void* d_out, int out_size, void* d_ws, size_t ws_size,
                              hipStream_t stream) {
  const int* x      = (const int*)d_in[0];
  const float* emb  = (const float*)d_in[1];
  const float* W_ih = (const float*)d_in[2];
  const float* W_hh = (const float*)d_in[3];
  const float* b_ih = (const float*)d_in[4];
  const float* b_hh = (const float*)d_in[5];
  const float* W_out = (const float*)d_in[6];
  const float* b_out = (const float*)d_in[7];
  const float* h0   = (const float*)d_in[8];
  const float* c0   = (const float*)d_in[9];
  float* out = (float*)d_out;

  // workspace (~691 MB): XEall region is DEAD after xproj -> reused as the h ring.
  char* w = (char*)d_ws;
  u16* WihP = (u16*)w;   w += (size_t)G4_ * H_ * 2;             // 8 MB
  u16* WhhP = (u16*)w;   w += (size_t)G4_ * H_ * 2;             // 8 MB
  u16* XEall = (u16*)w;  w += (size_t)T_ * HB_ * 2;             // 128 MB (= hring[1..64])
  u16* GX2  = (u16*)w;   w += (size_t)T_ * NBLK_ * 512 * 16 * 2;  // 512 MB rec-ordered
  u16* h0slot = (u16*)w; w += (size_t)HB_ * 2;                  // 2 MB (hring[0])
  float* bcP = (float*)w;     w += (size_t)G4_ * 4;
  float* partAll = (float*)w; w += (size_t)T_ * PARTSZ_ * 4;    // 32 MB
  u32* flags = (u32*)w;       w += (size_t)T_ * NBLK_ * 4;      // 128 KB

  prep_gather_kernel<<<70689, 256, 0, stream>>>(x, emb, W_ih, W_hh, b_ih, b_hh, h0,
                                                XEall, WihP, WhhP, bcP, h0slot, flags);
  xproj_kernel<<<8192, 512, 0, stream>>>(XEall, WihP, bcP, GX2);
  rec_kernel<<<NBLK_, 512, 0, stream>>>(h0slot, XEall /*hring[1..]*/, WhhP, GX2, c0,
                                        partAll, W_out, flags);
  final_kernel<<<512, 256, 0, stream>>>(partAll, b_out, out);
}